// Round 1
// 192.759 us; speedup vs baseline: 1.3469x; 1.3469x over previous
//
#include <hip/hip_runtime.h>
#include <hip/hip_fp16.h>
#include <math.h>

#define N_NODES 50000
#define N_EDGES 800000
#define DIM 64
#define N_LAYERS 5

#define BLK 128      // two waves per block
#define ROWS 32      // 16 rows per wave
#define HSTRIDE 68   // 16B-aligned rows for ds_read_b128
#define POOL_REP 16

#define NB 196       // coarse buckets = ceil(N_NODES/256)
#define CAPB 5632    // fixed region per bucket (mean 4082, sigma ~64)
#define EPB (N_EDGES / 256)   // 3125 edges per bfill2 block

#define EBCAP 512    // per-wave LDS edge-index buffer (span ~Poisson(256), 16 sigma margin)

#define WFRAG_PER_LAYER (3 * 2 * 4 * 64 * 8)   // 12288 shorts (hi-only)
#define XP (N_NODES * DIM / 4)                  // 800000 xprep items (4 elems each)
#define WP (N_LAYERS * WFRAG_PER_LAYER)         // 61440 wprep items

typedef __attribute__((ext_vector_type(8))) short short8;
typedef __attribute__((ext_vector_type(4))) float floatx4;

__device__ inline unsigned short bf16_rne(float f) {
    unsigned int u = __float_as_uint(f);
    return (unsigned short)((u + 0x7FFFu + ((u >> 16) & 1u)) >> 16);
}
__device__ inline float bf16_f(unsigned short h) {
    return __uint_as_float(((unsigned int)h) << 16);
}
// fp8 e5m2 = top byte of fp16. Decode: 2 ops. Encode: f32->f16 RNE, then RNE on 8-bit boundary.
__device__ inline float e5m2_f32(unsigned char b) {
    return __half2float(__ushort_as_half((unsigned short)((unsigned short)b << 8)));
}
__device__ inline unsigned char f32_e5m2(float f) {
    unsigned short us = __half_as_ushort(__float2half(f));
    us = (unsigned short)(us + 0x7F + ((us >> 8) & 1));
    return (unsigned char)(us >> 8);
}
// Pack bytes {b0,b1} / {b2,b3} of a dword into half2 {b<<8, b'<<8} via v_perm_b32.
// src0 = 0 so selector indices 4..7 safely produce zero bytes.
__device__ inline __half2 e5m2x2_lo(unsigned d) {
    unsigned h = __builtin_amdgcn_perm(0u, d, 0x01050004u);  // bytes [0,b0,0,b1]
    return __builtin_bit_cast(__half2, h);
}
__device__ inline __half2 e5m2x2_hi(unsigned d) {
    unsigned h = __builtin_amdgcn_perm(0u, d, 0x03070206u);  // bytes [0,b2,0,b3]
    return __builtin_bit_cast(__half2, h);
}

// ---------------- fused prep: x->fp8, W->bf16 frags (hi only), zero bucketCnt+pooled ----------------
__global__ __launch_bounds__(256) void prep_kernel(const float* __restrict__ x,
                                                   const float* __restrict__ W,
                                                   unsigned char* __restrict__ x8,
                                                   unsigned short* __restrict__ wfrag,
                                                   int* __restrict__ bucketCnt,
                                                   float* __restrict__ pooled) {
    int i = blockIdx.x * 256 + threadIdx.x;
    if (i < XP) {
        float4 v = ((const float4*)x)[i];
        uchar4 u;
        u.x = f32_e5m2(v.x); u.y = f32_e5m2(v.y);
        u.z = f32_e5m2(v.z); u.w = f32_e5m2(v.w);
        ((uchar4*)x8)[i] = u;
        return;
    }
    i -= XP;
    if (i < WP) {
        int t = i;
        int j    = t & 7;
        int lane = (t >> 3) & 63;
        int nt   = (t >> 9) & 3;
        int kt   = (t >> 11) & 1;
        int rest = t >> 12;
        int p    = rest % 3;
        int layer= rest / 3;
        int k = kt * 32 + (lane >> 4) * 8 + j;
        int n = nt * 16 + (lane & 15);
        float v = W[(((size_t)layer * 3 + p) * 64 + k) * 64 + n];
        wfrag[t] = bf16_rne(v);
        return;
    }
    i -= WP;
    if (i < NB) { bucketCnt[i] = 0; return; }
    i -= NB;
    if (i < N_LAYERS * POOL_REP * DIM) pooled[i] = 0.f;
}

// ---------------- bucketed CSR build (R11/R14 proven) ----------------
__global__ __launch_bounds__(256) void bfill2_kernel(const int* __restrict__ src,
                                                     const int* __restrict__ dst,
                                                     int* __restrict__ bucketCnt,
                                                     int* __restrict__ ebuf) {
    __shared__ int cnt[NB];
    __shared__ int basev[NB];
    const int t = threadIdx.x;
    const int e0 = blockIdx.x * EPB;
    if (t < NB) cnt[t] = 0;
    __syncthreads();
    for (int i = t; i < EPB; i += 256)
        atomicAdd(&cnt[dst[e0 + i] >> 8], 1);
    __syncthreads();
    if (t < NB) {
        int c = cnt[t];
        basev[t] = c ? atomicAdd(&bucketCnt[t], c) : 0;
        cnt[t] = 0;   // reuse as in-block cursor
    }
    __syncthreads();
    for (int i = t; i < EPB; i += 256) {
        int d = dst[e0 + i];
        int b = d >> 8;
        int pos = atomicAdd(&cnt[b], 1);
        ebuf[(size_t)b * CAPB + basev[b] + pos] = ((d & 255) << 16) | src[e0 + i];
    }
}

__global__ __launch_bounds__(256) void bbuild_kernel(const int* __restrict__ ebuf,
                                                     const int* __restrict__ bucketCnt,
                                                     int* __restrict__ rowptr,
                                                     int* __restrict__ csr_src) {
    __shared__ int red[256];
    __shared__ int cnt[256];
    __shared__ int scan[256];
    __shared__ int cur[256];
    __shared__ int lds_e[CAPB];
    const int t = threadIdx.x;
    const int b = blockIdx.x;

    red[t] = (t < b && t < NB) ? bucketCnt[t] : 0;
    __syncthreads();
    #pragma unroll
    for (int off = 128; off > 0; off >>= 1) {
        if (t < off) red[t] += red[t + off];
        __syncthreads();
    }
    const int base  = red[0];
    const int cnt_b = bucketCnt[b];
    const int* __restrict__ ereg = ebuf + (size_t)b * CAPB;

    cnt[t] = 0;
    __syncthreads();
    for (int i = t; i < cnt_b; i += 256) {
        int v = ereg[i];
        lds_e[i] = v;
        atomicAdd(&cnt[v >> 16], 1);
    }
    __syncthreads();
    scan[t] = cnt[t];
    __syncthreads();
    #pragma unroll
    for (int off = 1; off < 256; off <<= 1) {
        int u = (t >= off) ? scan[t - off] : 0;
        __syncthreads();
        scan[t] += u;
        __syncthreads();
    }
    int excl = scan[t] - cnt[t];
    rowptr[b * 256 + t] = base + excl;
    cur[t] = excl;
    __syncthreads();
    for (int i = t; i < cnt_b; i += 256) {
        int v = lds_e[i];
        int pos = atomicAdd(&cur[v >> 16], 1);
        csr_src[base + pos] = v & 0xFFFF;
    }
}

// ---------------- fused layer (fp8 h; quad-per-row dword gather; hi-only bf16 MFMA MLP) ----------------
__global__ __launch_bounds__(BLK) void layer_kernel(const unsigned char* __restrict__ h8,
                                                    const int* __restrict__ rowptr,
                                                    const int* __restrict__ csr_src,
                                                    const unsigned short* __restrict__ wf,
                                                    unsigned char* __restrict__ h_out,
                                                    float* __restrict__ pooled) {  // [POOL_REP][64]
    __shared__ float H[ROWS * HSTRIDE];   // 8.7 KB
    __shared__ int EB[2][EBCAP];          // 4 KB: per-wave staged edge-index span
    const int tid  = threadIdx.x;
    const int lane = tid & 63;
    const int w    = __builtin_amdgcn_readfirstlane(tid >> 6);
    const int n0   = blockIdx.x * ROWS;
    const int nw   = n0 + w * 16;
    const int c4   = (lane & 15) << 2;    // this lane's 4-dim slot within a row
    const int q    = lane >> 4;           // quad id: which row of the group this lane serves

    int rpv = rowptr[nw + min(lane, 16)];
    const int e0w  = __builtin_amdgcn_readlane(rpv, 0);
    const int span = __builtin_amdgcn_readlane(rpv, 16) - e0w;

    if (span <= EBCAP) {
        // ---- stage the wave's contiguous csr span into LDS (coalesced) ----
        for (int i = lane; i < span; i += 64)
            EB[w][i] = csr_src[e0w + i];
        // wave-synchronous LDS use: drain this wave's ds_writes before cross-lane reads
        asm volatile("s_waitcnt lgkmcnt(0)" ::: "memory");
        const int* eb = &EB[w][0];

        // ---- 4 groups of 4 rows; quad q owns row 4g+q; lane holds dims [4c,4c+3] ----
        for (int g = 0; g < 4; ++g) {
            const int myrow = 4 * g + q;
            const int e0q = __shfl(rpv, myrow, 64);
            const int deg = __shfl(rpv, myrow + 1, 64) - e0q;
            int Rm = deg;
            Rm = max(Rm, __shfl_xor(Rm, 16, 64));
            Rm = max(Rm, __shfl_xor(Rm, 32, 64));      // group max over the 4 quads
            const int Rpad = (Rm + 7) & ~7;            // unroll-8 rounds, pads self-cancel
            const int rowq = nw + myrow;
            const int ob   = e0q - e0w;

            __half2 a01 = __float2half2_rn(0.f);       // packed f16 accumulation (dims 4c,4c+1)
            __half2 a23 = __float2half2_rn(0.f);       // (dims 4c+2,4c+3)

            for (int i = 0; i < Rpad; i += 8) {
                unsigned dv[8];
                #pragma unroll
                for (int k = 0; k < 8; ++k) {
                    // LDS overreads beyond span are pads only -> value replaced below
                    int ev = eb[ob + i + k];
                    int s  = (i + k < deg) ? ev : rowq;
                    dv[k] = *(const unsigned*)(h8 + (((unsigned)s << 6) | (unsigned)c4));
                }
                #pragma unroll
                for (int k = 0; k < 8; ++k) {
                    a01 = __hadd2(a01, e5m2x2_lo(dv[k]));
                    a23 = __hadd2(a23, e5m2x2_hi(dv[k]));
                }
            }

            // self + exact pad-cancellation: pads added self Rpad-deg times
            unsigned sd = *(const unsigned*)(h8 + (((unsigned)rowq << 6) | (unsigned)c4));
            float scale = (float)(1 - (Rpad - deg));
            float2 f01 = __half22float2(a01);
            float2 f23 = __half22float2(a23);
            float4 r;
            r.x = f01.x + e5m2_f32((unsigned char)(sd      )) * scale;
            r.y = f01.y + e5m2_f32((unsigned char)(sd >>  8)) * scale;
            r.z = f23.x + e5m2_f32((unsigned char)(sd >> 16)) * scale;
            r.w = f23.y + e5m2_f32((unsigned char)(sd >> 24)) * scale;
            if (rowq >= N_NODES) { r.x = 0.f; r.y = 0.f; r.z = 0.f; r.w = 0.f; }
            *(float4*)&H[(w * 16 + myrow) * HSTRIDE + c4] = r;
        }
    } else {
        // ---- rare fallback (span > EBCAP): chunked 64-lane byte gather, any degree ----
        for (int j = 0; j < 16; ++j) {
            const int n = nw + j;
            const int e0 = __builtin_amdgcn_readlane(rpv, j);
            const int e1 = __builtin_amdgcn_readlane(rpv, j + 1);
            float acc = 0.f;
            if (n < N_NODES) {
                float self = e5m2_f32(h8[(size_t)n * DIM + lane]);
                acc = self;
                for (int base = e0; base < e1; base += 64) {
                    const int m  = min(64, e1 - base);
                    const int mr = (m + 3) & ~3;
                    int idx = (lane < m) ? csr_src[base + lane] : n;
                    acc -= (float)(mr - m) * self;
                    for (int jj = 0; jj < mr; jj += 4) {
                        int s0 = __builtin_amdgcn_readlane(idx, jj + 0);
                        int s1 = __builtin_amdgcn_readlane(idx, jj + 1);
                        int s2 = __builtin_amdgcn_readlane(idx, jj + 2);
                        int s3 = __builtin_amdgcn_readlane(idx, jj + 3);
                        float v0 = e5m2_f32(h8[(size_t)s0 * DIM + lane]);
                        float v1 = e5m2_f32(h8[(size_t)s1 * DIM + lane]);
                        float v2 = e5m2_f32(h8[(size_t)s2 * DIM + lane]);
                        float v3 = e5m2_f32(h8[(size_t)s3 * DIM + lane]);
                        acc += (v0 + v1) + (v2 + v3);
                    }
                }
            }
            H[(w * 16 + j) * HSTRIDE + lane] = acc;
        }
    }
    __syncthreads();

    // ---- MLP: hi-only bf16 MFMA (noise << fp8 storage noise already in pipeline) ----
    const int mrow = lane & 15;
    const int quad = lane >> 4;
    const short8* Bf = (const short8*)wf;

    for (int p = 0; p < 3; ++p) {
        short8 Ahi[2];
        #pragma unroll
        for (int kt = 0; kt < 2; ++kt) {
            const float* ap = &H[(w * 16 + mrow) * HSTRIDE + kt * 32 + quad * 8];
            float4 f0 = *(const float4*)ap;
            float4 f1 = *(const float4*)(ap + 4);
            float fv[8] = {f0.x, f0.y, f0.z, f0.w, f1.x, f1.y, f1.z, f1.w};
            short8 hi;
            #pragma unroll
            for (int jj = 0; jj < 8; ++jj)
                hi[jj] = (short)bf16_rne(fv[jj]);
            Ahi[kt] = hi;
        }

        floatx4 acc[4];
        #pragma unroll
        for (int nt = 0; nt < 4; ++nt) { acc[nt][0]=0.f; acc[nt][1]=0.f; acc[nt][2]=0.f; acc[nt][3]=0.f; }

        #pragma unroll
        for (int nt = 0; nt < 4; ++nt) {
            #pragma unroll
            for (int kt = 0; kt < 2; ++kt) {
                int fbase = ((p * 2 + kt) * 4 + nt) * 64 + lane;
                short8 bhi = Bf[fbase];
                acc[nt] = __builtin_amdgcn_mfma_f32_16x16x32_bf16(Ahi[kt], bhi, acc[nt], 0, 0, 0);
            }
        }
        __syncthreads();
        #pragma unroll
        for (int nt = 0; nt < 4; ++nt) {
            #pragma unroll
            for (int reg = 0; reg < 4; ++reg) {
                int row = w * 16 + quad * 4 + reg;
                H[row * HSTRIDE + nt * 16 + mrow] = fmaxf(acc[nt][reg], 0.f);
            }
        }
        __syncthreads();
    }

    // ---- store h as fp8 e5m2 for next layer (coalesced uchar4, guarded tail) ----
    #pragma unroll
    for (int i = 0; i < 4; ++i) {
        int t4 = tid + i * BLK;
        int r  = t4 >> 4;
        int c  = (t4 & 15) << 2;
        int grow = n0 + r;
        if (grow < N_NODES) {
            float4 v = *(const float4*)&H[r * HSTRIDE + c];
            uchar4 u;
            u.x = f32_e5m2(v.x); u.y = f32_e5m2(v.y);
            u.z = f32_e5m2(v.z); u.w = f32_e5m2(v.w);
            *(uchar4*)(h_out + (size_t)grow * DIM + c) = u;
        }
    }

    // ---- pool partial (fp32 H; invalid rows hold exact zeros) ----
    if (tid < 64) {
        float s = 0.f;
        #pragma unroll
        for (int r = 0; r < ROWS; ++r)
            s += H[r * HSTRIDE + tid];
        atomicAdd(&pooled[(blockIdx.x & (POOL_REP - 1)) * DIM + tid], s);
    }
}

__global__ void finalize_kernel(const float* __restrict__ pooled,  // [L][POOL_REP][64]
                                const float* __restrict__ Wl,
                                float* __restrict__ out) {
    int c = threadIdx.x;  // 64
    float s = 0.f;
    #pragma unroll
    for (int l = 0; l < N_LAYERS; ++l) {
        float col = 0.f;
        #pragma unroll
        for (int r = 0; r < POOL_REP; ++r)
            col += pooled[(l * POOL_REP + r) * DIM + c];
        s += col * Wl[l * DIM + c];
    }
    #pragma unroll
    for (int off = 32; off > 0; off >>= 1)
        s += __shfl_down(s, off, 64);
    if (c == 0) {
        float logit = s / (float)N_NODES;
        out[0] = 1.f / (1.f + expf(-logit));
    }
}

extern "C" void kernel_launch(void* const* d_in, const int* in_sizes, int n_in,
                              void* d_out, int out_size, void* d_ws, size_t ws_size,
                              hipStream_t stream) {
    const float* x   = (const float*)d_in[0];
    const float* W   = (const float*)d_in[1];
    const float* Wl  = (const float*)d_in[2];
    const int*   src = (const int*)d_in[3];
    const int*   dst = (const int*)d_in[4];
    float* out = (float*)d_out;

    char* ws = (char*)d_ws;
    const size_t h8Bytes = (size_t)N_NODES * DIM;                     // 3.2 MB
    unsigned char* hX = (unsigned char*)(ws);
    unsigned char* hA = (unsigned char*)(ws + h8Bytes);
    unsigned char* hB = (unsigned char*)(ws + 2 * h8Bytes);
    int*   csr_src  = (int*)  (ws + 3 * h8Bytes);                     // 3.2 MB
    int*   ebuf     = csr_src + N_EDGES;                              // NB*CAPB
    int*   rowptr   = ebuf + (size_t)NB * CAPB;                       // NB*256 = 50176
    int*   bucketCnt= rowptr + NB * 256;                              // NB
    float* pooled   = (float*)(bucketCnt + NB);                       // 5*16*64 floats
    unsigned short* wfrag = (unsigned short*)(pooled + N_LAYERS * POOL_REP * DIM);

    const int prepItems = XP + WP + NB + N_LAYERS * POOL_REP * DIM;
    prep_kernel<<<(prepItems + 255) / 256, 256, 0, stream>>>(x, W, hX, wfrag, bucketCnt, pooled);
    bfill2_kernel<<<256, 256, 0, stream>>>(src, dst, bucketCnt, ebuf);
    bbuild_kernel<<<NB, 256, 0, stream>>>(ebuf, bucketCnt, rowptr, csr_src);

    const unsigned char* hcur = hX;
    unsigned char* hnext = hA;
    const int grid = (N_NODES + ROWS - 1) / ROWS;   // 1563
    for (int l = 0; l < N_LAYERS; ++l) {
        layer_kernel<<<grid, BLK, 0, stream>>>(
            hcur, rowptr, csr_src, wfrag + (size_t)l * WFRAG_PER_LAYER, hnext,
            pooled + (size_t)l * POOL_REP * DIM);
        hcur = hnext;
        hnext = (hnext == hA) ? hB : hA;
    }
    finalize_kernel<<<1, 64, 0, stream>>>(pooled, Wl, out);
}

// Round 2
// 186.413 us; speedup vs baseline: 1.3928x; 1.0340x over previous
//
#include <hip/hip_runtime.h>
#include <hip/hip_fp16.h>
#include <math.h>

#define N_NODES 50000
#define N_EDGES 800000
#define DIM 64
#define N_LAYERS 5

#define BLK 128      // two waves per block
#define ROWS 32      // 16 rows per wave
#define HSTRIDE 68   // 16B-aligned rows for ds_read_b128
#define POOL_REP 16

#define NB 196       // coarse buckets = ceil(N_NODES/256)
#define CAPB 5632    // fixed region per bucket (mean 4082, sigma ~64)
#define BF2_BLOCKS 512
#define EPB2 ((N_EDGES + BF2_BLOCKS - 1) / BF2_BLOCKS)   // 1563 edges per bfill2 block

#define EBCAP 512    // per-wave LDS edge-index buffer (span ~Poisson(256), 16 sigma margin)

#define WFRAG_PER_LAYER (3 * 2 * 4 * 64 * 8)   // 12288 shorts (hi-only)
#define XP (N_NODES * DIM / 4)                  // 800000 xprep items (4 elems each)
#define WP (N_LAYERS * WFRAG_PER_LAYER)         // 61440 wprep items

typedef __attribute__((ext_vector_type(8))) short short8;
typedef __attribute__((ext_vector_type(4))) float floatx4;

__device__ inline unsigned short bf16_rne(float f) {
    unsigned int u = __float_as_uint(f);
    return (unsigned short)((u + 0x7FFFu + ((u >> 16) & 1u)) >> 16);
}
// fp8 e5m2 = top byte of fp16. Decode: 2 ops. Encode: f32->f16 RNE, then RNE on 8-bit boundary.
__device__ inline float e5m2_f32(unsigned char b) {
    return __half2float(__ushort_as_half((unsigned short)((unsigned short)b << 8)));
}
__device__ inline unsigned char f32_e5m2(float f) {
    unsigned short us = __half_as_ushort(__float2half(f));
    us = (unsigned short)(us + 0x7F + ((us >> 8) & 1));
    return (unsigned char)(us >> 8);
}
// Pack bytes {b0,b1} / {b2,b3} of a dword into half2 {b<<8, b'<<8} via v_perm_b32.
__device__ inline __half2 e5m2x2_lo(unsigned d) {
    unsigned h = __builtin_amdgcn_perm(0u, d, 0x01050004u);  // bytes [0,b0,0,b1]
    return __builtin_bit_cast(__half2, h);
}
__device__ inline __half2 e5m2x2_hi(unsigned d) {
    unsigned h = __builtin_amdgcn_perm(0u, d, 0x03070206u);  // bytes [0,b2,0,b3]
    return __builtin_bit_cast(__half2, h);
}

// ---------------- fused prep: x->fp8, W->bf16 frags (hi only), zero bucketCnt+pooled ----------------
__global__ __launch_bounds__(256) void prep_kernel(const float* __restrict__ x,
                                                   const float* __restrict__ W,
                                                   unsigned char* __restrict__ x8,
                                                   unsigned short* __restrict__ wfrag,
                                                   int* __restrict__ bucketCnt,
                                                   float* __restrict__ pooled) {
    int i = blockIdx.x * 256 + threadIdx.x;
    if (i < XP) {
        float4 v = ((const float4*)x)[i];
        uchar4 u;
        u.x = f32_e5m2(v.x); u.y = f32_e5m2(v.y);
        u.z = f32_e5m2(v.z); u.w = f32_e5m2(v.w);
        ((uchar4*)x8)[i] = u;
        return;
    }
    i -= XP;
    if (i < WP) {
        int t = i;
        int j    = t & 7;
        int lane = (t >> 3) & 63;
        int nt   = (t >> 9) & 3;
        int kt   = (t >> 11) & 1;
        int rest = t >> 12;
        int p    = rest % 3;
        int layer= rest / 3;
        int k = kt * 32 + (lane >> 4) * 8 + j;
        int n = nt * 16 + (lane & 15);
        float v = W[(((size_t)layer * 3 + p) * 64 + k) * 64 + n];
        wfrag[t] = bf16_rne(v);
        return;
    }
    i -= WP;
    if (i < NB) { bucketCnt[i] = 0; return; }
    i -= NB;
    if (i < N_LAYERS * POOL_REP * DIM) pooled[i] = 0.f;
}

// ---------------- bucketed CSR build: phase 1 (512 blocks for atomic spread) ----------------
__global__ __launch_bounds__(256) void bfill2_kernel(const int* __restrict__ src,
                                                     const int* __restrict__ dst,
                                                     int* __restrict__ bucketCnt,
                                                     int* __restrict__ ebuf) {
    __shared__ int cnt[NB];
    __shared__ int basev[NB];
    const int t = threadIdx.x;
    const int e0 = blockIdx.x * EPB2;
    if (t < NB) cnt[t] = 0;
    __syncthreads();
    for (int i = t; i < EPB2; i += 256) {
        int e = e0 + i;
        if (e < N_EDGES) atomicAdd(&cnt[dst[e] >> 8], 1);
    }
    __syncthreads();
    if (t < NB) {
        int c = cnt[t];
        basev[t] = c ? atomicAdd(&bucketCnt[t], c) : 0;
        cnt[t] = 0;   // reuse as in-block cursor
    }
    __syncthreads();
    for (int i = t; i < EPB2; i += 256) {
        int e = e0 + i;
        if (e < N_EDGES) {
            int d = dst[e];
            int b = d >> 8;
            int pos = atomicAdd(&cnt[b], 1);
            ebuf[(size_t)b * CAPB + basev[b] + pos] = ((d & 255) << 16) | src[e];
        }
    }
}

// ---------------- phase 2: 8 waves, shuffle-scan (4 barriers instead of ~20) ----------------
__global__ __launch_bounds__(512) void bbuild_kernel(const int* __restrict__ ebuf,
                                                     const int* __restrict__ bucketCnt,
                                                     int* __restrict__ rowptr,
                                                     int* __restrict__ csr_src) {
    __shared__ int cnt[256];
    __shared__ int cur[256];
    __shared__ int wred[8];
    __shared__ int wscan[4];
    __shared__ int lds_e[CAPB];
    const int t = threadIdx.x;       // 0..511
    const int lane = t & 63;
    const int wv = t >> 6;           // 0..7
    const int b = blockIdx.x;

    // base = sum_{j<b} bucketCnt[j] via wave butterfly reduce
    int v = (t < b && t < NB) ? bucketCnt[t] : 0;
    #pragma unroll
    for (int off = 32; off > 0; off >>= 1) v += __shfl_xor(v, off, 64);
    if (lane == 0) wred[wv] = v;
    if (t < 256) cnt[t] = 0;
    __syncthreads();
    const int base  = wred[0] + wred[1] + wred[2] + wred[3];
    const int cnt_b = bucketCnt[b];
    const int* __restrict__ ereg = ebuf + (size_t)b * CAPB;

    for (int i = t; i < cnt_b; i += 512) {
        int e = ereg[i];
        lds_e[i] = e;
        atomicAdd(&cnt[e >> 16], 1);
    }
    __syncthreads();

    // inclusive shuffle-scan of cnt[256] by waves 0..3
    int excl = 0;
    if (t < 256) {
        int s = cnt[t];
        #pragma unroll
        for (int off = 1; off < 64; off <<= 1) {
            int u = __shfl_up(s, off, 64);
            if (lane >= off) s += u;
        }
        if (lane == 63) wscan[wv] = s;
        excl = s - cnt[t];
    }
    __syncthreads();
    if (t < 256) {
        int woff = 0;
        #pragma unroll
        for (int j = 0; j < 4; ++j) if (j < wv) woff += wscan[j];
        excl += woff;
        rowptr[b * 256 + t] = base + excl;
        cur[t] = excl;
    }
    __syncthreads();
    for (int i = t; i < cnt_b; i += 512) {
        int e = lds_e[i];
        int pos = atomicAdd(&cur[e >> 16], 1);
        csr_src[base + pos] = e & 0xFFFF;
    }
}

// ---------------- fused layer (fp8 h; octet-per-row dwordx2 gather; wave-private LDS, 1 barrier) ----------------
__global__ __launch_bounds__(BLK) void layer_kernel(const unsigned char* __restrict__ h8,
                                                    const int* __restrict__ rowptr,
                                                    const int* __restrict__ csr_src,
                                                    const unsigned short* __restrict__ wf,
                                                    unsigned char* __restrict__ h_out,
                                                    float* __restrict__ pooled) {  // [POOL_REP][64]
    __shared__ float H[ROWS * HSTRIDE];   // 8.7 KB
    __shared__ int EB[2][EBCAP];          // 4 KB: per-wave staged edge-index span (pre-shifted <<6)
    const int tid  = threadIdx.x;
    const int lane = tid & 63;
    const int w    = __builtin_amdgcn_readfirstlane(tid >> 6);
    const int n0   = blockIdx.x * ROWS;
    const int nw   = n0 + w * 16;
    const int o8   = (lane & 7) << 3;     // byte offset of this lane's 8 dims
    const int rg   = lane >> 3;           // row-octet id 0..7

    int rpv = rowptr[nw + min(lane, 16)];
    const int e0w  = __builtin_amdgcn_readlane(rpv, 0);
    const int span = __builtin_amdgcn_readlane(rpv, 16) - e0w;

    if (span <= EBCAP) {
        // stage wave's contiguous csr span into LDS, pre-shifted into byte offsets
        for (int i = lane; i < span; i += 64)
            EB[w][i] = csr_src[e0w + i] << 6;
        asm volatile("s_waitcnt lgkmcnt(0)" ::: "memory");
        const int* eb = &EB[w][0];

        // 2 groups of 8 rows; octet rg owns row 8g+rg; lane holds dims [o8/... +8)
        for (int g = 0; g < 2; ++g) {
            const int myrow = g * 8 + rg;
            const int e0q = __shfl(rpv, myrow, 64);
            const int deg = __shfl(rpv, myrow + 1, 64) - e0q;
            int Rm = deg;
            Rm = max(Rm, __shfl_xor(Rm, 8, 64));
            Rm = max(Rm, __shfl_xor(Rm, 16, 64));
            Rm = max(Rm, __shfl_xor(Rm, 32, 64));   // max over the 8 rows -> wave-uniform
            const int Rpad = (Rm + 7) & ~7;
            const int rowq = nw + myrow;
            const int rq6  = rowq << 6;
            const int ob   = e0q - e0w;

            __half2 a01 = __float2half2_rn(0.f);
            __half2 a23 = a01, a45 = a01, a67 = a01;

            for (int i = 0; i < Rpad; i += 8) {
                uint2 dv[8];
                #pragma unroll
                for (int k = 0; k < 8; ++k) {
                    int s6 = eb[ob + i + k];           // overreads are pad slots, replaced below
                    s6 = (i + k < deg) ? s6 : rq6;
                    dv[k] = *(const uint2*)(h8 + (unsigned)(s6 | o8));
                }
                #pragma unroll
                for (int k = 0; k < 8; ++k) {
                    a01 = __hadd2(a01, e5m2x2_lo(dv[k].x));
                    a23 = __hadd2(a23, e5m2x2_hi(dv[k].x));
                    a45 = __hadd2(a45, e5m2x2_lo(dv[k].y));
                    a67 = __hadd2(a67, e5m2x2_hi(dv[k].y));
                }
            }

            // self + exact pad-cancellation (pads added self Rpad-deg times)
            uint2 sd = *(const uint2*)(h8 + (unsigned)(rq6 | o8));
            float scale = (float)(1 - (Rpad - deg));
            float2 f01 = __half22float2(a01), f23 = __half22float2(a23);
            float2 f45 = __half22float2(a45), f67 = __half22float2(a67);
            float4 r0, r1;
            r0.x = f01.x + e5m2_f32((unsigned char)(sd.x      )) * scale;
            r0.y = f01.y + e5m2_f32((unsigned char)(sd.x >>  8)) * scale;
            r0.z = f23.x + e5m2_f32((unsigned char)(sd.x >> 16)) * scale;
            r0.w = f23.y + e5m2_f32((unsigned char)(sd.x >> 24)) * scale;
            r1.x = f45.x + e5m2_f32((unsigned char)(sd.y      )) * scale;
            r1.y = f45.y + e5m2_f32((unsigned char)(sd.y >>  8)) * scale;
            r1.z = f67.x + e5m2_f32((unsigned char)(sd.y >> 16)) * scale;
            r1.w = f67.y + e5m2_f32((unsigned char)(sd.y >> 24)) * scale;
            if (rowq >= N_NODES) {
                r0.x = 0.f; r0.y = 0.f; r0.z = 0.f; r0.w = 0.f;
                r1.x = 0.f; r1.y = 0.f; r1.z = 0.f; r1.w = 0.f;
            }
            float* hp = &H[(w * 16 + myrow) * HSTRIDE + o8];
            *(float4*)hp = r0;
            *(float4*)(hp + 4) = r1;
        }
    } else {
        // rare fallback (span > EBCAP): chunked 64-lane byte gather, any degree
        for (int j = 0; j < 16; ++j) {
            const int n = nw + j;
            const int e0 = __builtin_amdgcn_readlane(rpv, j);
            const int e1 = __builtin_amdgcn_readlane(rpv, j + 1);
            float acc = 0.f;
            if (n < N_NODES) {
                float self = e5m2_f32(h8[(size_t)n * DIM + lane]);
                acc = self;
                for (int base = e0; base < e1; base += 64) {
                    const int m  = min(64, e1 - base);
                    const int mr = (m + 3) & ~3;
                    int idx = (lane < m) ? csr_src[base + lane] : n;
                    acc -= (float)(mr - m) * self;
                    for (int jj = 0; jj < mr; jj += 4) {
                        int s0 = __builtin_amdgcn_readlane(idx, jj + 0);
                        int s1 = __builtin_amdgcn_readlane(idx, jj + 1);
                        int s2 = __builtin_amdgcn_readlane(idx, jj + 2);
                        int s3 = __builtin_amdgcn_readlane(idx, jj + 3);
                        float v0 = e5m2_f32(h8[(size_t)s0 * DIM + lane]);
                        float v1 = e5m2_f32(h8[(size_t)s1 * DIM + lane]);
                        float v2 = e5m2_f32(h8[(size_t)s2 * DIM + lane]);
                        float v3 = e5m2_f32(h8[(size_t)s3 * DIM + lane]);
                        acc += (v0 + v1) + (v2 + v3);
                    }
                }
            }
            H[(w * 16 + j) * HSTRIDE + lane] = acc;
        }
    }
    // no __syncthreads: aggregation, MFMA A/outputs, relu writes all stay within
    // this wave's 16 H rows; per-wave DS-pipe ordering guarantees RAW/WAR.
    asm volatile("s_waitcnt lgkmcnt(0)" ::: "memory");

    // ---- MLP: hi-only bf16 MFMA (wave-private in H; zero inter-stage barriers) ----
    const int mrow = lane & 15;
    const int quad = lane >> 4;
    const short8* Bf = (const short8*)wf;

    for (int p = 0; p < 3; ++p) {
        short8 Ahi[2];
        #pragma unroll
        for (int kt = 0; kt < 2; ++kt) {
            const float* ap = &H[(w * 16 + mrow) * HSTRIDE + kt * 32 + quad * 8];
            float4 f0 = *(const float4*)ap;
            float4 f1 = *(const float4*)(ap + 4);
            float fv[8] = {f0.x, f0.y, f0.z, f0.w, f1.x, f1.y, f1.z, f1.w};
            short8 hi;
            #pragma unroll
            for (int jj = 0; jj < 8; ++jj)
                hi[jj] = (short)bf16_rne(fv[jj]);
            Ahi[kt] = hi;
        }

        floatx4 acc[4];
        #pragma unroll
        for (int nt = 0; nt < 4; ++nt) { acc[nt][0]=0.f; acc[nt][1]=0.f; acc[nt][2]=0.f; acc[nt][3]=0.f; }

        #pragma unroll
        for (int nt = 0; nt < 4; ++nt) {
            #pragma unroll
            for (int kt = 0; kt < 2; ++kt) {
                int fbase = ((p * 2 + kt) * 4 + nt) * 64 + lane;
                short8 bhi = Bf[fbase];
                acc[nt] = __builtin_amdgcn_mfma_f32_16x16x32_bf16(Ahi[kt], bhi, acc[nt], 0, 0, 0);
            }
        }
        // relu-write back to this wave's own rows (reads above already completed: in-order DS pipe)
        #pragma unroll
        for (int nt = 0; nt < 4; ++nt) {
            #pragma unroll
            for (int reg = 0; reg < 4; ++reg) {
                int row = w * 16 + quad * 4 + reg;
                H[row * HSTRIDE + nt * 16 + mrow] = fmaxf(acc[nt][reg], 0.f);
            }
        }
    }
    __syncthreads();   // the ONE cross-wave barrier: store+pool read all 32 rows

    // ---- store h as fp8 e5m2 for next layer (coalesced uchar4, guarded tail) ----
    #pragma unroll
    for (int i = 0; i < 4; ++i) {
        int t4 = tid + i * BLK;
        int r  = t4 >> 4;
        int c  = (t4 & 15) << 2;
        int grow = n0 + r;
        if (grow < N_NODES) {
            float4 v = *(const float4*)&H[r * HSTRIDE + c];
            uchar4 u;
            u.x = f32_e5m2(v.x); u.y = f32_e5m2(v.y);
            u.z = f32_e5m2(v.z); u.w = f32_e5m2(v.w);
            *(uchar4*)(h_out + (size_t)grow * DIM + c) = u;
        }
    }

    // ---- pool partial (fp32 H; invalid rows hold exact zeros) ----
    if (tid < 64) {
        float s = 0.f;
        #pragma unroll
        for (int r = 0; r < ROWS; ++r)
            s += H[r * HSTRIDE + tid];
        atomicAdd(&pooled[(blockIdx.x & (POOL_REP - 1)) * DIM + tid], s);
    }
}

__global__ void finalize_kernel(const float* __restrict__ pooled,  // [L][POOL_REP][64]
                                const float* __restrict__ Wl,
                                float* __restrict__ out) {
    int c = threadIdx.x;  // 64
    float s = 0.f;
    #pragma unroll
    for (int l = 0; l < N_LAYERS; ++l) {
        float col = 0.f;
        #pragma unroll
        for (int r = 0; r < POOL_REP; ++r)
            col += pooled[(l * POOL_REP + r) * DIM + c];
        s += col * Wl[l * DIM + c];
    }
    #pragma unroll
    for (int off = 32; off > 0; off >>= 1)
        s += __shfl_down(s, off, 64);
    if (c == 0) {
        float logit = s / (float)N_NODES;
        out[0] = 1.f / (1.f + expf(-logit));
    }
}

extern "C" void kernel_launch(void* const* d_in, const int* in_sizes, int n_in,
                              void* d_out, int out_size, void* d_ws, size_t ws_size,
                              hipStream_t stream) {
    const float* x   = (const float*)d_in[0];
    const float* W   = (const float*)d_in[1];
    const float* Wl  = (const float*)d_in[2];
    const int*   src = (const int*)d_in[3];
    const int*   dst = (const int*)d_in[4];
    float* out = (float*)d_out;

    char* ws = (char*)d_ws;
    const size_t h8Bytes = (size_t)N_NODES * DIM;                     // 3.2 MB
    unsigned char* hX = (unsigned char*)(ws);
    unsigned char* hA = (unsigned char*)(ws + h8Bytes);
    unsigned char* hB = (unsigned char*)(ws + 2 * h8Bytes);
    int*   csr_src  = (int*)  (ws + 3 * h8Bytes);                     // 3.2 MB
    int*   ebuf     = csr_src + N_EDGES;                              // NB*CAPB
    int*   rowptr   = ebuf + (size_t)NB * CAPB;                       // NB*256 = 50176
    int*   bucketCnt= rowptr + NB * 256;                              // NB
    float* pooled   = (float*)(bucketCnt + NB);                       // 5*16*64 floats
    unsigned short* wfrag = (unsigned short*)(pooled + N_LAYERS * POOL_REP * DIM);

    const int prepItems = XP + WP + NB + N_LAYERS * POOL_REP * DIM;
    prep_kernel<<<(prepItems + 255) / 256, 256, 0, stream>>>(x, W, hX, wfrag, bucketCnt, pooled);
    bfill2_kernel<<<BF2_BLOCKS, 256, 0, stream>>>(src, dst, bucketCnt, ebuf);
    bbuild_kernel<<<NB, 512, 0, stream>>>(ebuf, bucketCnt, rowptr, csr_src);

    const unsigned char* hcur = hX;
    unsigned char* hnext = hA;
    const int grid = (N_NODES + ROWS - 1) / ROWS;   // 1563
    for (int l = 0; l < N_LAYERS; ++l) {
        layer_kernel<<<grid, BLK, 0, stream>>>(
            hcur, rowptr, csr_src, wfrag + (size_t)l * WFRAG_PER_LAYER, hnext,
            pooled + (size_t)l * POOL_REP * DIM);
        hcur = hnext;
        hnext = (hnext == hA) ? hB : hA;
    }
    finalize_kernel<<<1, 64, 0, stream>>>(pooled, Wl, out);
}